// Round 12
// baseline (315.273 us; speedup 1.0000x reference)
//
#include <hip/hip_runtime.h>

#define NPTS 8192
#define NB 4
#define KNN 16
#define DCH 64
#define CAP 128
#define WR 8
#define G 32
#define NC 32768          // G^3 cells
#define MCAP 2048         // staged-stream capacity per wave
#define SEGCAP 128
#define NCELL_CAP 2048    // window-cell cap: larger -> immediate fallback (no walk)
#define HCEL 0.3125f      // 10/G

// ws layout (bytes):
//   xq    : float4[NB*NPTS]      @ 0        (524288)  raw (x,y,z,|x|^2), ORIG order
//   xss   : float4[NB*NPTS]      @ 524288   (524288)  scaled (-2x,-2y,-2z,|x|^2), MORTON-SORTED
//   oidx  : ushort[NB*NPTS]      @ 1048576  (65536)   sorted pos -> orig local idx
//   ibuf  : ushort[NB*NPTS][16]  @ 1114112  (1048576) final knn orig ids per ORIG row
//   cellP : int[NB*NC]           @ 2162688  (524288)  hist -> excl prefix -> inclusive ends (morton id space)
//   stats : double[54]           @ 2686976  (pad 512)
//   ss    : float[128]           @ 2687488
#define WS_XQ 0
#define WS_XS 524288
#define WS_OI 1048576
#define WS_IB 1114112
#define WS_CP 2162688
#define WS_ST 2686976
#define WS_SS 2687488

__device__ __forceinline__ float vkey(float4 q, float4 c) {
    return __fmaf_rn(q.x, c.x, __fmaf_rn(q.y, c.y, __fmaf_rn(q.z, c.z, c.w)));
}

__device__ __forceinline__ int cellof(float v) {
    float t = (v + 5.0f) * 3.2f;
    t = fminf(fmaxf(t, 0.0f), 31.0f);
    return (int)t;
}

// spread 5 bits to positions 0,3,6,9,12
__device__ __forceinline__ unsigned mort5(unsigned v) {
    v = (v | (v << 8)) & 0x100Fu;
    v = (v | (v << 4)) & 0x10C3u;
    v = (v | (v << 2)) & 0x1249u;
    return v;
}
__device__ __forceinline__ unsigned mort3(int ix, int iy, int iz) {
    return mort5((unsigned)ix) | (mort5((unsigned)iy) << 1) | (mort5((unsigned)iz) << 2);
}

__device__ __forceinline__ int mbcnt64(unsigned long long m) {
    return __builtin_amdgcn_mbcnt_hi((unsigned)(m >> 32),
           __builtin_amdgcn_mbcnt_lo((unsigned)m, 0));
}

__global__ __launch_bounds__(256) void k1_prep(const float* __restrict__ x, float4* __restrict__ xq,
                                               int* __restrict__ cellP) {
    int p = blockIdx.x * 256 + threadIdx.x;
    if (p >= NB * NPTS) return;
    int b = p >> 13;
    float x0 = x[p * 3 + 0], x1 = x[p * 3 + 1], x2 = x[p * 3 + 2];
    float sq = __fmaf_rn(x0, x0, __fmaf_rn(x1, x1, x2 * x2));
    xq[p] = make_float4(x0, x1, x2, sq);
    int cid = (int)mort3(cellof(x0), cellof(x1), cellof(x2));
    atomicAdd(&cellP[b * NC + cid], 1);
}

__global__ __launch_bounds__(1024) void k0b_prefix(int* __restrict__ P) {
    __shared__ int part[1024];
    int t = threadIdx.x;
    int* Pb = P + blockIdx.x * NC;
    int loc[32];
    int s = 0;
    int base = t * 32;
#pragma unroll
    for (int i = 0; i < 32; ++i) { loc[i] = Pb[base + i]; s += loc[i]; }
    part[t] = s;
    __syncthreads();
    for (int off = 1; off < 1024; off <<= 1) {
        int v = part[t];
        if (t >= off) v += part[t - off];
        __syncthreads();
        part[t] = v;
        __syncthreads();
    }
    int run = (t == 0) ? 0 : part[t - 1];
#pragma unroll
    for (int i = 0; i < 32; ++i) { int c = loc[i]; Pb[base + i] = run; run += c; }
}

__global__ __launch_bounds__(256) void k0c_scatter(const float* __restrict__ x, int* __restrict__ cellP,
                                                   float4* __restrict__ xss, unsigned short* __restrict__ oidx) {
    int p = blockIdx.x * 256 + threadIdx.x;
    if (p >= NB * NPTS) return;
    int b = p >> 13, pl = p & (NPTS - 1);
    float x0 = x[p * 3 + 0], x1 = x[p * 3 + 1], x2 = x[p * 3 + 2];
    float sq = __fmaf_rn(x0, x0, __fmaf_rn(x1, x1, x2 * x2));
    int cid = (int)mort3(cellof(x0), cellof(x1), cellof(x2));
    int pos = atomicAdd(&cellP[b * NC + cid], 1);
    xss[b * NPTS + pos] = make_float4(-2.0f * x0, -2.0f * x1, -2.0f * x2, sq);
    oidx[b * NPTS + pos] = (unsigned short)pl;
}

// Exact KNN over a spatially pruned candidate stream (morton-sorted).
// tau0: 16th smallest v of 64 sorted-adjacent candidates (valid bound for any 64 reals).
// walk: lane-parallel over window cells, per-cell 3D box lb, morton lookup into cellP;
//       ballot-compact segment list; early break / pre-skip on overflow -> full-scan fb.
// passes A/B + exact tau + phase3: identical to R11-proven code.
__global__ __launch_bounds__(256, 3) void k2_knn(const float4* __restrict__ xq,
                                                 const float4* __restrict__ xss,
                                                 const unsigned short* __restrict__ oidx,
                                                 const int* __restrict__ cellP,
                                                 unsigned short* __restrict__ ibuf) {
    __shared__ float2 buf[4][WR][CAP];        // 32 KB; per wave: [0,2K)=vw, [2K,3K)=segs
    __shared__ unsigned short sidx[4][MCAP];  // 16 KB
    const int wave = threadIdx.x >> 6;
    const int lane = threadIdx.x & 63;
    const int b = blockIdx.x >> 8;
    const int js = (blockIdx.x & 255) * 32 + wave * WR;   // sorted row base
    const float4* xqb = xq + b * NPTS;
    const float4* xsb = xss + b * NPTS;
    const unsigned short* oib = oidx + b * NPTS;
    const int* Pb = cellP + b * NC;
    float* vw = (float*)&buf[wave][0][0];                       // 512 floats
    int* seg_s0 = (int*)((char*)&buf[wave][0][0] + 2048);       // 128 ints
    int* seg_ba = (int*)((char*)&buf[wave][0][0] + 2560);       // 128 ints

    float4 xi[WR];
    int orow[WR];
#pragma unroll
    for (int r = 0; r < WR; ++r) {
        int o = oib[js + r];
        orow[r] = o;
        xi[r] = xqb[o];
    }

    float bxl = xi[0].x, bxh = xi[0].x, byl = xi[0].y, byh = xi[0].y, bzl = xi[0].z, bzh = xi[0].z;
#pragma unroll
    for (int r = 1; r < WR; ++r) {
        bxl = fminf(bxl, xi[r].x); bxh = fmaxf(bxh, xi[r].x);
        byl = fminf(byl, xi[r].y); byh = fmaxf(byh, xi[r].y);
        bzl = fminf(bzl, xi[r].z); bzh = fmaxf(bzh, xi[r].z);
    }

    // ---- tau0: 16th smallest v over 64 sorted-adjacent candidates ----
    int w0 = js - 28;
    w0 = w0 < 0 ? 0 : (w0 > NPTS - 64 ? NPTS - 64 : w0);
    float4 cw = xsb[w0 + lane];
    float v0s[WR];
#pragma unroll
    for (int r = 0; r < WR; ++r) { v0s[r] = vkey(xi[r], cw); vw[r * 64 + lane] = v0s[r]; }
    __syncthreads();
    float taudmax = 0.0f;
#pragma unroll
    for (int r = 0; r < WR; ++r) {
        float mine = v0s[r];
        int rk = 0;
        const float4* vm4 = (const float4*)(vw + r * 64);
#pragma unroll
        for (int q = 0; q < 16; ++q) {
            float4 vv = vm4[q];
            int j0 = q * 4;
            rk += (vv.x < mine || (vv.x == mine && (j0 + 0) < lane)) ? 1 : 0;
            rk += (vv.y < mine || (vv.y == mine && (j0 + 1) < lane)) ? 1 : 0;
            rk += (vv.z < mine || (vv.z == mine && (j0 + 2) < lane)) ? 1 : 0;
            rk += (vv.w < mine || (vv.w == mine && (j0 + 3) < lane)) ? 1 : 0;
        }
        float v = (rk < KNN) ? mine : -3.0e38f;
#pragma unroll
        for (int o = 32; o > 0; o >>= 1) v = fmaxf(v, __shfl_xor(v, o));
        taudmax = fmaxf(taudmax, v + xi[r].w);
    }
    taudmax = fmaxf(taudmax, 0.0f);
    float rmax = sqrtf(taudmax);

    int cx0 = cellof(bxl - rmax), cx1 = cellof(bxh + rmax);
    int cy0 = cellof(byl - rmax), cy1 = cellof(byh + rmax);
    int cz0 = cellof(bzl - rmax), cz1 = cellof(bzh + rmax);
    int nx = cx1 - cx0 + 1, ny = cy1 - cy0 + 1, nz = cz1 - cz0 + 1;
    int ncells = nx * ny * nz;

    // ---- lane-parallel cell walk (skip entirely if window obviously too big) ----
    int Mtot = 0, nseg = 0;
    if (ncells <= NCELL_CAP) {
        for (int p0 = 0; p0 < ncells; p0 += 64) {
            int p = p0 + lane;
            int s0v = 0, len = 0;
            if (p < ncells) {
                int ix = p % nx;
                int t2 = p / nx;
                int iy = t2 % ny;
                int iz = t2 / ny;
                ix += cx0; iy += cy0; iz += cz0;
                float xl = (ix == 0) ? -1.0e30f : (-5.0f + ix * HCEL);
                float xh = (ix == G - 1) ? 1.0e30f : (-5.0f + (ix + 1) * HCEL);
                float dx = fmaxf(0.0f, fmaxf(xl - bxh, bxl - xh));
                float yl = (iy == 0) ? -1.0e30f : (-5.0f + iy * HCEL);
                float yh = (iy == G - 1) ? 1.0e30f : (-5.0f + (iy + 1) * HCEL);
                float dy = fmaxf(0.0f, fmaxf(yl - byh, byl - yh));
                float zl = (iz == 0) ? -1.0e30f : (-5.0f + iz * HCEL);
                float zh = (iz == G - 1) ? 1.0e30f : (-5.0f + (iz + 1) * HCEL);
                float dz = fmaxf(0.0f, fmaxf(zl - bzh, bzl - zh));
                float dd = __fmaf_rn(dx, dx, __fmaf_rn(dy, dy, dz * dz));
                if (dd <= taudmax) {
                    int m = (int)mort3(ix, iy, iz);
                    s0v = (m == 0) ? 0 : Pb[m - 1];
                    len = Pb[m] - s0v;
                }
            }
            bool have = (len > 0);
            unsigned long long m = __ballot(have);
            if (m) {
                int plen = have ? len : 0;
                int scan = plen;
#pragma unroll
                for (int o = 1; o < 64; o <<= 1) {
                    int u = __shfl_up(scan, o);
                    if (lane >= o) scan += u;
                }
                if (have) {
                    int si = nseg + mbcnt64(m);
                    if (si < SEGCAP) { seg_s0[si] = s0v; seg_ba[si] = Mtot + (scan - plen); }
                }
                nseg += (int)__popcll(m);
                Mtot += __shfl(scan, 63);
            }
            if (Mtot > MCAP || nseg > SEGCAP) break;   // uniform; bounded wasted work
        }
    }

    const bool fb = (ncells > NCELL_CAP) || (Mtot > MCAP) || (nseg > SEGCAP);
    const int Ms = fb ? NPTS : Mtot;

    // ---- pack: segment-major LDS burst ----
    if (!fb) {
        for (int s = 0; s < nseg; ++s) {
            int s0v = seg_s0[s];
            int bs = seg_ba[s];
            int ls = ((s + 1 < nseg) ? seg_ba[s + 1] : Mtot) - bs;
            for (int t = lane; t < ls; t += 64) sidx[wave][bs + t] = (unsigned short)(s0v + t);
        }
    }
    __syncthreads();

    // ---- pass A: lane minima over the stream ----
    float mn[WR];
#pragma unroll
    for (int r = 0; r < WR; ++r) mn[r] = 3.0e38f;
    for (int q0 = 0; q0 < Ms; q0 += 64) {
        int t_ = q0 + lane;
        bool act = t_ < Ms;
        int idx = fb ? t_ : (int)sidx[wave][act ? t_ : 0];
        float4 c = act ? xsb[idx] : make_float4(0.0f, 0.0f, 0.0f, 3.0e38f);
#pragma unroll
        for (int r = 0; r < WR; ++r) mn[r] = fminf(mn[r], vkey(xi[r], c));
    }

    // ---- final tau: exact 16th smallest of the 64 lane-minima ----
#pragma unroll
    for (int r = 0; r < WR; ++r) vw[r * 64 + lane] = mn[r];
    __syncthreads();
    float tau[WR];
#pragma unroll
    for (int r = 0; r < WR; ++r) {
        float mine = mn[r];
        int rk = 0;
        const float4* vm4 = (const float4*)(vw + r * 64);
#pragma unroll
        for (int q = 0; q < 16; ++q) {
            float4 vv = vm4[q];
            int j0 = q * 4;
            rk += (vv.x < mine || (vv.x == mine && (j0 + 0) < lane)) ? 1 : 0;
            rk += (vv.y < mine || (vv.y == mine && (j0 + 1) < lane)) ? 1 : 0;
            rk += (vv.z < mine || (vv.z == mine && (j0 + 2) < lane)) ? 1 : 0;
            rk += (vv.w < mine || (vv.w == mine && (j0 + 3) < lane)) ? 1 : 0;
        }
        float v = (rk < KNN) ? mine : -3.0e38f;
#pragma unroll
        for (int o = 32; o > 0; o >>= 1) v = fmaxf(v, __shfl_xor(v, o));
        tau[r] = v;
    }

    // ---- pass B: ballot-append (v, orig) for v <= tau ----
    int cnt[WR];
#pragma unroll
    for (int r = 0; r < WR; ++r) cnt[r] = 0;
    for (int q0 = 0; q0 < Ms; q0 += 64) {
        int t_ = q0 + lane;
        bool act = t_ < Ms;
        int idx = fb ? t_ : (int)sidx[wave][act ? t_ : 0];
        float4 c = act ? xsb[idx] : make_float4(0.0f, 0.0f, 0.0f, 3.0e38f);
        float fo = act ? (float)oib[idx] : 0.0f;
#pragma unroll
        for (int r = 0; r < WR; ++r) {
            float v = vkey(xi[r], c);
            bool p = (v <= tau[r]);
            unsigned long long m = __ballot(p);
            if (m) {
                if (p) {
                    int pos = cnt[r] + mbcnt64(m);
                    if (pos < CAP) buf[wave][r][pos] = make_float2(v, fo);
                }
                cnt[r] += (int)__popcll(m);
            }
        }
    }

    __syncthreads();

    // ---- phase 3: exact top-16 by (v, orig) rank count ----
#pragma unroll
    for (int rr = 0; rr < WR; ++rr) {
        int n = cnt[rr];
        n = (n < CAP) ? n : CAP;
        int l1 = lane + 64;
        bool v0 = (lane < n), v1 = (l1 < n);
        float2 e0 = buf[wave][rr][v0 ? lane : 0];
        float2 e1 = buf[wave][rr][v1 ? l1 : 0];
        int r0 = 0, r1 = 0;
        for (int j = 0; j < n; ++j) {
            float2 fj = buf[wave][rr][j];
            r0 += (fj.x < e0.x || (fj.x == e0.x && fj.y < e0.y)) ? 1 : 0;
            r1 += (fj.x < e1.x || (fj.x == e1.x && fj.y < e1.y)) ? 1 : 0;
        }
        size_t grow = (size_t)(b * NPTS + orow[rr]) * KNN;
        if (v0 && r0 < KNN) ibuf[grow + r0] = (unsigned short)(int)e0.y;
        if (v1 && r1 < KNN) ibuf[grow + r1] = (unsigned short)(int)e1.y;
    }
}

__global__ __launch_bounds__(256) void k3_moments(const float4* __restrict__ xq,
                                                  const unsigned short* __restrict__ ibuf,
                                                  double* __restrict__ stats) {
    __shared__ float red[4][54];
    int p = blockIdx.x * 256 + threadIdx.x;
    int b = p >> 13;
    const float4* xb = xq + b * NPTS;
    const unsigned short* ib = ibuf + (size_t)p * KNN;
    float4 xi = xb[p & (NPTS - 1)];

    float acc[54];
#pragma unroll
    for (int i = 0; i < 54; ++i) acc[i] = 0.0f;

#pragma unroll
    for (int k = 0; k < KNN; ++k) {
        int j = ib[k];
        float4 cj = xb[j];
        float f[9] = {xi.x, xi.y, xi.z, cj.x - xi.x, cj.y - xi.y, cj.z - xi.z, cj.x, cj.y, cj.z};
        int t = 9;
#pragma unroll
        for (int a = 0; a < 9; ++a) {
            acc[a] += f[a];
#pragma unroll
            for (int c = a; c < 9; ++c) { acc[t] += f[a] * f[c]; ++t; }
        }
    }

#pragma unroll
    for (int i = 0; i < 54; ++i) {
        float v = acc[i];
        for (int o = 32; o > 0; o >>= 1) v += __shfl_down(v, o);
        acc[i] = v;
    }
    int lane = threadIdx.x & 63;
    int wv = threadIdx.x >> 6;
    if (lane == 0) {
#pragma unroll
        for (int i = 0; i < 54; ++i) red[wv][i] = acc[i];
    }
    __syncthreads();
    if (threadIdx.x < 54) {
        float s = red[0][threadIdx.x] + red[1][threadIdx.x] + red[2][threadIdx.x] + red[3][threadIdx.x];
        atomicAdd(&stats[threadIdx.x], (double)s);
    }
}

__global__ void k4_finalize(const double* __restrict__ stats, const float* __restrict__ W,
                            const float* __restrict__ bias, const float* __restrict__ gamma,
                            const float* __restrict__ beta, float* __restrict__ ss) {
    int d = threadIdx.x;
    if (d >= DCH) return;
    const double M = (double)NB * NPTS * KNN;  // 524288
    double w[9];
    for (int c = 0; c < 9; ++c) w[c] = (double)W[c * DCH + d];
    double mf[9];
    for (int a = 0; a < 9; ++a) mf[a] = stats[a] / M;
    double q1 = 0.0;
    for (int a = 0; a < 9; ++a) q1 += mf[a] * w[a];
    double q2 = 0.0;
    int t = 0;
    for (int a = 0; a < 9; ++a) {
        for (int c = a; c < 9; ++c) {
            double pv = stats[9 + t] / M;
            double term = pv * w[a] * w[c];
            q2 += (a == c) ? term : 2.0 * term;
            ++t;
        }
    }
    double bd = (double)bias[d];
    double mean = q1 + bd;
    double ehh = q2 + 2.0 * bd * q1 + bd * bd;
    double var = ehh - mean * mean;
    double sc = (double)gamma[d] / sqrt(var + 1e-5);
    double sh = (double)beta[d] + sc * (bd - mean);
    ss[d] = (float)sc;
    ss[DCH + d] = (float)sh;
}

__global__ __launch_bounds__(256) void k5_out(const float4* __restrict__ xq,
                                              const unsigned short* __restrict__ ibuf,
                                              const float* __restrict__ W, const float* __restrict__ ss,
                                              float* __restrict__ out) {
    __shared__ float Ws[9 * DCH];
    __shared__ float scs[DCH], shs[DCH];
    for (int i = threadIdx.x; i < 9 * DCH; i += 256) Ws[i] = W[i];
    if (threadIdx.x < DCH) {
        scs[threadIdx.x] = ss[threadIdx.x];
        shs[threadIdx.x] = ss[DCH + threadIdx.x];
    }
    __syncthreads();

    int pt = blockIdx.x * 32 + (threadIdx.x >> 3);
    int oc = (threadIdx.x & 7) * 8;
    int b = pt >> 13;
    const float4* xb = xq + b * NPTS;
    float4 xi = xb[pt & (NPTS - 1)];

    float w[9][8];
#pragma unroll
    for (int c = 0; c < 9; ++c)
#pragma unroll
        for (int d = 0; d < 8; ++d) w[c][d] = Ws[c * DCH + oc + d];
    float sc[8], sh[8], y[8];
#pragma unroll
    for (int d = 0; d < 8; ++d) {
        sc[d] = scs[oc + d];
        sh[d] = shs[oc + d];
        y[d] = 0.0f;
    }

    const unsigned short* ib = ibuf + (size_t)pt * KNN;
#pragma unroll
    for (int k = 0; k < KNN; ++k) {
        int j = ib[k];
        float4 cj = xb[j];
        float f[9] = {xi.x, xi.y, xi.z, cj.x - xi.x, cj.y - xi.y, cj.z - xi.z, cj.x, cj.y, cj.z};
        float h[8];
#pragma unroll
        for (int d = 0; d < 8; ++d) h[d] = 0.0f;
#pragma unroll
        for (int c = 0; c < 9; ++c)
#pragma unroll
            for (int d = 0; d < 8; ++d) h[d] = __fmaf_rn(f[c], w[c][d], h[d]);
#pragma unroll
        for (int d = 0; d < 8; ++d) {
            float v = __fmaf_rn(sc[d], h[d], sh[d]);
            y[d] = fmaxf(y[d], fmaxf(v, 0.0f));
        }
    }
    float4* o4 = (float4*)(out + (size_t)pt * DCH + oc);
    o4[0] = make_float4(y[0], y[1], y[2], y[3]);
    o4[1] = make_float4(y[4], y[5], y[6], y[7]);
}

extern "C" void kernel_launch(void* const* d_in, const int* in_sizes, int n_in,
                              void* d_out, int out_size, void* d_ws, size_t ws_size,
                              hipStream_t stream) {
    const float* x = (const float*)d_in[0];
    const float* W = (const float*)d_in[1];
    const float* bias = (const float*)d_in[2];
    const float* gamma = (const float*)d_in[3];
    const float* beta = (const float*)d_in[4];
    float* out = (float*)d_out;
    char* ws = (char*)d_ws;

    float4* xq = (float4*)(ws + WS_XQ);
    float4* xss = (float4*)(ws + WS_XS);
    unsigned short* oidx = (unsigned short*)(ws + WS_OI);
    unsigned short* ibuf = (unsigned short*)(ws + WS_IB);
    int* cellP = (int*)(ws + WS_CP);
    double* stats = (double*)(ws + WS_ST);
    float* ss = (float*)(ws + WS_SS);

    hipMemsetAsync(cellP, 0, NB * NC * sizeof(int), stream);
    hipMemsetAsync(stats, 0, 54 * sizeof(double), stream);
    k1_prep<<<128, 256, 0, stream>>>(x, xq, cellP);
    k0b_prefix<<<NB, 1024, 0, stream>>>(cellP);
    k0c_scatter<<<128, 256, 0, stream>>>(x, cellP, xss, oidx);
    k2_knn<<<1024, 256, 0, stream>>>(xq, xss, oidx, cellP, ibuf);
    k3_moments<<<128, 256, 0, stream>>>(xq, ibuf, stats);
    k4_finalize<<<1, 64, 0, stream>>>(stats, W, bias, gamma, beta, ss);
    k5_out<<<1024, 256, 0, stream>>>(xq, ibuf, W, ss, out);
}

// Round 13
// 140.598 us; speedup vs baseline: 2.2424x; 2.2424x over previous
//
#include <hip/hip_runtime.h>

#define NPTS 8192
#define NB 4
#define KNN 16
#define DCH 64
#define CAP 128
#define WR 8

// ws layout (bytes):
//   xq4   : float4[NB*NPTS]  @ 0        (524288)   raw (x,y,z,|x|^2)  -- queries, k3, k5
//   xs4   : float4[NB*NPTS]  @ 524288   (524288)   scaled (-2x,-2y,-2z,|x|^2) -- k2 scans
//   ibuf  : ushort[NB*NPTS][16] @ 1048576 (1048576) final knn ids per row
//   stats : double[54]       @ 2097152  (432, pad 512)
//   ss    : float[128]       @ 2097664
#define WS_XQ 0
#define WS_XS 524288
#define WS_IB 1048576
#define WS_ST 2097152
#define WS_SS 2097664

// Selection key on prescaled candidate c' = (-2cx,-2cy,-2cz,|c|^2):
//   v = q.x*c'.x + q.y*c'.y + q.z*c'.z + c'.w = -2*dot(q,c) + |c|^2
// d = v + |q|^2 with |q|^2 constant per row => ranking by v == ranking by d.
__device__ __forceinline__ float vkey(float4 q, float4 c) {
    return __fmaf_rn(q.x, c.x, __fmaf_rn(q.y, c.y, __fmaf_rn(q.z, c.z, c.w)));
}

__global__ __launch_bounds__(256) void k1_prep(const float* __restrict__ x, float4* __restrict__ xq,
                                               float4* __restrict__ xs) {
    int p = blockIdx.x * 256 + threadIdx.x;
    if (p >= NB * NPTS) return;
    float x0 = x[p * 3 + 0], x1 = x[p * 3 + 1], x2 = x[p * 3 + 2];
    float sq = __fmaf_rn(x0, x0, __fmaf_rn(x1, x1, x2 * x2));
    xq[p] = make_float4(x0, x1, x2, sq);
    xs[p] = make_float4(-2.0f * x0, -2.0f * x1, -2.0f * x2, sq);
}

// wave-per-8-rows exact KNN via threshold filter (R9 structure, depth-3 prefetch).
// phase1: per-lane min over its 128-candidate slice (2 cands/iter, loads 2 iters ahead)
// tau   : 16th smallest of the 64 lane-minima via LDS rank-count
// phase2: rescan, ballot-append all v <= tau to wave-private LDS buffer
// phase3: exact rank-count top-16 of buffer (ties by smaller index, matches top_k)
// LDS = 32KB buf + 8KB vmin = 40960 B -> 4 blocks/CU.
__global__ __launch_bounds__(256, 4) void k2_knn(const float4* __restrict__ xq,
                                                 const float4* __restrict__ xs,
                                                 unsigned short* __restrict__ ibuf) {
    __shared__ float2 buf[4][WR][CAP];   // 32 KB
    __shared__ float vmin[4][WR][64];    // 8 KB
    const int wave = threadIdx.x >> 6;
    const int lane = threadIdx.x & 63;
    const int b = blockIdx.x >> 8;                 // 256 blocks per batch
    const int blkrow = (blockIdx.x & 255) * (4 * WR);
    const float4* xb = xq + b * NPTS;
    const float4* xc = xs + b * NPTS;
    const int rowbase = blkrow + wave * WR;

    float4 xi[WR];
#pragma unroll
    for (int r = 0; r < WR; ++r) xi[r] = xb[rowbase + r];   // raw queries, broadcast loads

    // ---- phase 1: lane-slice minima (depth-3 pipelined, no guards) ----
    float mn[WR];
#pragma unroll
    for (int r = 0; r < WR; ++r) mn[r] = 3.0e38f;

    {
        float4 a0 = xc[lane], a1 = xc[64 + lane];
        float4 b0 = xc[128 + lane], b1 = xc[192 + lane];
        for (int c0 = 0; c0 < NPTS; c0 += 128) {
            float4 n0 = xc[(c0 + 256 + lane) & (NPTS - 1)];   // 2 iters ahead (wraps, L1-hot)
            float4 n1 = xc[(c0 + 320 + lane) & (NPTS - 1)];
#pragma unroll
            for (int r = 0; r < WR; ++r) {
                float v0 = vkey(xi[r], a0);
                float v1 = vkey(xi[r], a1);
                mn[r] = fminf(mn[r], fminf(v0, v1));   // -> v_min3_f32
            }
            a0 = b0; a1 = b1; b0 = n0; b1 = n1;
        }
    }

    // ---- tau per row: 16th smallest of the 64 lane-minima ----
#pragma unroll
    for (int r = 0; r < WR; ++r) vmin[wave][r][lane] = mn[r];
    __syncthreads();   // hard fence: all vmin writes visible before the broadcast reads

    float tau[WR];
#pragma unroll
    for (int r = 0; r < WR; ++r) {
        float mine = mn[r];
        int rk = 0;
        const float4* vm4 = (const float4*)(&vmin[wave][r][0]);
#pragma unroll
        for (int q = 0; q < 16; ++q) {
            float4 vv = vm4[q];   // broadcast read, conflict-free
            int j0 = q * 4;
            rk += (vv.x < mine || (vv.x == mine && (j0 + 0) < lane)) ? 1 : 0;
            rk += (vv.y < mine || (vv.y == mine && (j0 + 1) < lane)) ? 1 : 0;
            rk += (vv.z < mine || (vv.z == mine && (j0 + 2) < lane)) ? 1 : 0;
            rk += (vv.w < mine || (vv.w == mine && (j0 + 3) < lane)) ? 1 : 0;
        }
        // lanes with rk<16 hold exactly the 16 smallest (lex); tau = max of their values
        float v = (rk < KNN) ? mine : -3.0e38f;
#pragma unroll
        for (int o = 32; o > 0; o >>= 1) v = fmaxf(v, __shfl_xor(v, o));
        tau[r] = v;
    }

    // ---- phase 2: filtered collection (depth-3 pipelined ballot compaction) ----
    int cnt[WR];
#pragma unroll
    for (int r = 0; r < WR; ++r) cnt[r] = 0;

    {
        float4 a0 = xc[lane], a1 = xc[64 + lane];
        float4 b0 = xc[128 + lane], b1 = xc[192 + lane];
        for (int c0 = 0; c0 < NPTS; c0 += 128) {
            float4 n0 = xc[(c0 + 256 + lane) & (NPTS - 1)];
            float4 n1 = xc[(c0 + 320 + lane) & (NPTS - 1)];
            float f0 = (float)(c0 + lane);
            float f1 = (float)(c0 + 64 + lane);
#pragma unroll
            for (int r = 0; r < WR; ++r) {
                float v0 = vkey(xi[r], a0);
                bool p0 = (v0 <= tau[r]);
                unsigned long long m0 = __ballot(p0);
                if (m0) {
                    if (p0) {
                        int ofs = __builtin_amdgcn_mbcnt_hi((unsigned)(m0 >> 32),
                                  __builtin_amdgcn_mbcnt_lo((unsigned)m0, 0));
                        int pos = cnt[r] + ofs;
                        if (pos < CAP) buf[wave][r][pos] = make_float2(v0, f0);
                    }
                    cnt[r] += (int)__popcll(m0);
                }
                float v1 = vkey(xi[r], a1);
                bool p1 = (v1 <= tau[r]);
                unsigned long long m1 = __ballot(p1);
                if (m1) {
                    if (p1) {
                        int ofs = __builtin_amdgcn_mbcnt_hi((unsigned)(m1 >> 32),
                                  __builtin_amdgcn_mbcnt_lo((unsigned)m1, 0));
                        int pos = cnt[r] + ofs;
                        if (pos < CAP) buf[wave][r][pos] = make_float2(v1, f1);
                    }
                    cnt[r] += (int)__popcll(m1);
                }
            }
            a0 = b0; a1 = b1; b0 = n0; b1 = n1;
        }
    }

    __syncthreads();   // hard ordering: all buf writes visible before phase 3 reads

    // ---- phase 3: exact top-16 of buffer by rank count ----
#pragma unroll
    for (int rr = 0; rr < WR; ++rr) {
        int n = cnt[rr];
        n = (n < CAP) ? n : CAP;
        int l1 = lane + 64;
        bool v0 = (lane < n), v1 = (l1 < n);
        float2 e0 = buf[wave][rr][v0 ? lane : 0];
        float2 e1 = buf[wave][rr][v1 ? l1 : 0];
        int r0 = 0, r1 = 0;
        for (int j = 0; j < n; ++j) {
            float2 fj = buf[wave][rr][j];   // broadcast read
            r0 += (fj.x < e0.x || (fj.x == e0.x && fj.y < e0.y)) ? 1 : 0;
            r1 += (fj.x < e1.x || (fj.x == e1.x && fj.y < e1.y)) ? 1 : 0;
        }
        size_t grow = (size_t)(b * NPTS + rowbase + rr) * KNN;
        if (v0 && r0 < KNN) ibuf[grow + r0] = (unsigned short)(int)e0.y;
        if (v1 && r1 < KNN) ibuf[grow + r1] = (unsigned short)(int)e1.y;
    }
}

// moments over the 16 selected neighbors: acc[0..8]=sum f, acc[9..53]=sum f_a f_c (upper tri)
__global__ __launch_bounds__(256) void k3_moments(const float4* __restrict__ xq,
                                                  const unsigned short* __restrict__ ibuf,
                                                  double* __restrict__ stats) {
    __shared__ float red[4][54];
    int p = blockIdx.x * 256 + threadIdx.x;
    int b = p >> 13;
    const float4* xb = xq + b * NPTS;
    const unsigned short* ib = ibuf + (size_t)p * KNN;
    float4 xi = xb[p & (NPTS - 1)];

    float acc[54];
#pragma unroll
    for (int i = 0; i < 54; ++i) acc[i] = 0.0f;

#pragma unroll
    for (int k = 0; k < KNN; ++k) {
        int j = ib[k];
        float4 cj = xb[j];
        float f[9] = {xi.x, xi.y, xi.z, cj.x - xi.x, cj.y - xi.y, cj.z - xi.z, cj.x, cj.y, cj.z};
        int t = 9;
#pragma unroll
        for (int a = 0; a < 9; ++a) {
            acc[a] += f[a];
#pragma unroll
            for (int c = a; c < 9; ++c) { acc[t] += f[a] * f[c]; ++t; }
        }
    }

#pragma unroll
    for (int i = 0; i < 54; ++i) {
        float v = acc[i];
        for (int o = 32; o > 0; o >>= 1) v += __shfl_down(v, o);
        acc[i] = v;
    }
    int lane = threadIdx.x & 63;
    int wv = threadIdx.x >> 6;
    if (lane == 0) {
#pragma unroll
        for (int i = 0; i < 54; ++i) red[wv][i] = acc[i];
    }
    __syncthreads();
    if (threadIdx.x < 54) {
        float s = red[0][threadIdx.x] + red[1][threadIdx.x] + red[2][threadIdx.x] + red[3][threadIdx.x];
        atomicAdd(&stats[threadIdx.x], (double)s);
    }
}

__global__ void k4_finalize(const double* __restrict__ stats, const float* __restrict__ W,
                            const float* __restrict__ bias, const float* __restrict__ gamma,
                            const float* __restrict__ beta, float* __restrict__ ss) {
    int d = threadIdx.x;
    if (d >= DCH) return;
    const double M = (double)NB * NPTS * KNN;  // 524288
    double w[9];
    for (int c = 0; c < 9; ++c) w[c] = (double)W[c * DCH + d];
    double mf[9];
    for (int a = 0; a < 9; ++a) mf[a] = stats[a] / M;
    double q1 = 0.0;
    for (int a = 0; a < 9; ++a) q1 += mf[a] * w[a];
    double q2 = 0.0;
    int t = 0;
    for (int a = 0; a < 9; ++a) {
        for (int c = a; c < 9; ++c) {
            double pv = stats[9 + t] / M;
            double term = pv * w[a] * w[c];
            q2 += (a == c) ? term : 2.0 * term;
            ++t;
        }
    }
    double bd = (double)bias[d];
    double mean = q1 + bd;
    double ehh = q2 + 2.0 * bd * q1 + bd * bd;
    double var = ehh - mean * mean;
    double sc = (double)gamma[d] / sqrt(var + 1e-5);
    double sh = (double)beta[d] + sc * (bd - mean);
    ss[d] = (float)sc;
    ss[DCH + d] = (float)sh;
}

// 8 threads per point, 8 channels each: h = f.W (W in regs), y = max_k relu(sc*h+sh)
__global__ __launch_bounds__(256) void k5_out(const float4* __restrict__ xq,
                                              const unsigned short* __restrict__ ibuf,
                                              const float* __restrict__ W, const float* __restrict__ ss,
                                              float* __restrict__ out) {
    __shared__ float Ws[9 * DCH];
    __shared__ float scs[DCH], shs[DCH];
    for (int i = threadIdx.x; i < 9 * DCH; i += 256) Ws[i] = W[i];
    if (threadIdx.x < DCH) {
        scs[threadIdx.x] = ss[threadIdx.x];
        shs[threadIdx.x] = ss[DCH + threadIdx.x];
    }
    __syncthreads();

    int pt = blockIdx.x * 32 + (threadIdx.x >> 3);
    int oc = (threadIdx.x & 7) * 8;
    int b = pt >> 13;
    const float4* xb = xq + b * NPTS;
    float4 xi = xb[pt & (NPTS - 1)];

    float w[9][8];
#pragma unroll
    for (int c = 0; c < 9; ++c)
#pragma unroll
        for (int d = 0; d < 8; ++d) w[c][d] = Ws[c * DCH + oc + d];
    float sc[8], sh[8], y[8];
#pragma unroll
    for (int d = 0; d < 8; ++d) {
        sc[d] = scs[oc + d];
        sh[d] = shs[oc + d];
        y[d] = 0.0f;
    }

    const unsigned short* ib = ibuf + (size_t)pt * KNN;
#pragma unroll
    for (int k = 0; k < KNN; ++k) {
        int j = ib[k];
        float4 cj = xb[j];
        float f[9] = {xi.x, xi.y, xi.z, cj.x - xi.x, cj.y - xi.y, cj.z - xi.z, cj.x, cj.y, cj.z};
        float h[8];
#pragma unroll
        for (int d = 0; d < 8; ++d) h[d] = 0.0f;
#pragma unroll
        for (int c = 0; c < 9; ++c)
#pragma unroll
            for (int d = 0; d < 8; ++d) h[d] = __fmaf_rn(f[c], w[c][d], h[d]);
#pragma unroll
        for (int d = 0; d < 8; ++d) {
            float v = __fmaf_rn(sc[d], h[d], sh[d]);
            y[d] = fmaxf(y[d], fmaxf(v, 0.0f));
        }
    }
    float4* o4 = (float4*)(out + (size_t)pt * DCH + oc);
    o4[0] = make_float4(y[0], y[1], y[2], y[3]);
    o4[1] = make_float4(y[4], y[5], y[6], y[7]);
}

extern "C" void kernel_launch(void* const* d_in, const int* in_sizes, int n_in,
                              void* d_out, int out_size, void* d_ws, size_t ws_size,
                              hipStream_t stream) {
    const float* x = (const float*)d_in[0];
    const float* W = (const float*)d_in[1];
    const float* bias = (const float*)d_in[2];
    const float* gamma = (const float*)d_in[3];
    const float* beta = (const float*)d_in[4];
    float* out = (float*)d_out;
    char* ws = (char*)d_ws;

    float4* xq = (float4*)(ws + WS_XQ);
    float4* xs = (float4*)(ws + WS_XS);
    unsigned short* ibuf = (unsigned short*)(ws + WS_IB);
    double* stats = (double*)(ws + WS_ST);
    float* ss = (float*)(ws + WS_SS);

    hipMemsetAsync(stats, 0, 54 * sizeof(double), stream);
    k1_prep<<<128, 256, 0, stream>>>(x, xq, xs);
    k2_knn<<<1024, 256, 0, stream>>>(xq, xs, ibuf);
    k3_moments<<<128, 256, 0, stream>>>(xq, ibuf, stats);
    k4_finalize<<<1, 64, 0, stream>>>(stats, W, bias, gamma, beta, ss);
    k5_out<<<1024, 256, 0, stream>>>(xq, ibuf, W, ss, out);
}

// Round 14
// 136.428 us; speedup vs baseline: 2.3109x; 1.0306x over previous
//
#include <hip/hip_runtime.h>

#define NPTS 8192
#define NB 4
#define KNN 16
#define DCH 64
#define CAP 128
#define WR 8

// ws layout (bytes):
//   xq4   : float4[NB*NPTS]  @ 0        (524288)   raw (x,y,z,|x|^2)  -- queries, k3, k5
//   xs4   : float4[NB*NPTS]  @ 524288   (524288)   scaled (-2x,-2y,-2z,|x|^2) -- k2 scans
//   ibuf  : ushort[NB*NPTS][16] @ 1048576 (1048576) final knn ids per row
//   stats : double[54]       @ 2097152  (432, pad 512)
//   ss    : float[128]       @ 2097664
#define WS_XQ 0
#define WS_XS 524288
#define WS_IB 1048576
#define WS_ST 2097152
#define WS_SS 2097664

// Selection key on prescaled candidate c' = (-2cx,-2cy,-2cz,|c|^2):
//   v = q.x*c'.x + q.y*c'.y + q.z*c'.z + c'.w = -2*dot(q,c) + |c|^2
// d = v + |q|^2 with |q|^2 constant per row => ranking by v == ranking by d.
__device__ __forceinline__ float vkey(float4 q, float4 c) {
    return __fmaf_rn(q.x, c.x, __fmaf_rn(q.y, c.y, __fmaf_rn(q.z, c.z, c.w)));
}

__global__ __launch_bounds__(256) void k1_prep(const float* __restrict__ x, float4* __restrict__ xq,
                                               float4* __restrict__ xs) {
    int p = blockIdx.x * 256 + threadIdx.x;
    if (p >= NB * NPTS) return;
    float x0 = x[p * 3 + 0], x1 = x[p * 3 + 1], x2 = x[p * 3 + 2];
    float sq = __fmaf_rn(x0, x0, __fmaf_rn(x1, x1, x2 * x2));
    xq[p] = make_float4(x0, x1, x2, sq);
    xs[p] = make_float4(-2.0f * x0, -2.0f * x1, -2.0f * x2, sq);
}

// wave-per-8-rows exact KNN via threshold filter.
// All scan loads share ONE base pointer with imm offsets 0/1024/2048/3072 (13-bit range);
// next-iter prefetch via pn=p+256. 4 cands/lane/iter, final iteration peeled (no guards,
// no wrap arithmetic). tau/ballot/phase-3 logic identical to the R9/R13-proven kernel.
__global__ __launch_bounds__(256, 4) void k2_knn(const float4* __restrict__ xq,
                                                 const float4* __restrict__ xs,
                                                 unsigned short* __restrict__ ibuf) {
    __shared__ float2 buf[4][WR][CAP];   // 32 KB
    __shared__ float vmin[4][WR][64];    // 8 KB
    const int wave = threadIdx.x >> 6;
    const int lane = threadIdx.x & 63;
    const int b = blockIdx.x >> 8;                 // 256 blocks per batch
    const int blkrow = (blockIdx.x & 255) * (4 * WR);
    const float4* xb = xq + b * NPTS;
    const float4* xc = xs + b * NPTS;
    const int rowbase = blkrow + wave * WR;

    float4 xi[WR];
#pragma unroll
    for (int r = 0; r < WR; ++r) xi[r] = xb[rowbase + r];   // raw queries, broadcast loads

    // ---- phase 1: lane-slice minima (4 cands/iter, imm-offset loads, peeled tail) ----
    float mn[WR];
#pragma unroll
    for (int r = 0; r < WR; ++r) mn[r] = 3.0e38f;

    {
        const float4* p = xc + lane;
        float4 a0 = p[0], a1 = p[64], a2 = p[128], a3 = p[192];
        for (int c0 = 0; c0 < NPTS - 256; c0 += 256) {
            const float4* pn = p + 256;
            float4 b0 = pn[0], b1 = pn[64], b2 = pn[128], b3 = pn[192];
#pragma unroll
            for (int r = 0; r < WR; ++r) {
                float v0 = vkey(xi[r], a0);
                float v1 = vkey(xi[r], a1);
                float v2 = vkey(xi[r], a2);
                float v3 = vkey(xi[r], a3);
                mn[r] = fminf(mn[r], fminf(v0, v1));   // -> v_min3_f32
                mn[r] = fminf(mn[r], fminf(v2, v3));
            }
            a0 = b0; a1 = b1; a2 = b2; a3 = b3; p = pn;
        }
#pragma unroll
        for (int r = 0; r < WR; ++r) {
            float v0 = vkey(xi[r], a0);
            float v1 = vkey(xi[r], a1);
            float v2 = vkey(xi[r], a2);
            float v3 = vkey(xi[r], a3);
            mn[r] = fminf(mn[r], fminf(v0, v1));
            mn[r] = fminf(mn[r], fminf(v2, v3));
        }
    }

    // ---- tau per row: 16th smallest of the 64 lane-minima ----
#pragma unroll
    for (int r = 0; r < WR; ++r) vmin[wave][r][lane] = mn[r];
    __syncthreads();   // hard fence: all vmin writes visible before the broadcast reads

    float tau[WR];
#pragma unroll
    for (int r = 0; r < WR; ++r) {
        float mine = mn[r];
        int rk = 0;
        const float4* vm4 = (const float4*)(&vmin[wave][r][0]);
#pragma unroll
        for (int q = 0; q < 16; ++q) {
            float4 vv = vm4[q];   // broadcast read, conflict-free
            int j0 = q * 4;
            rk += (vv.x < mine || (vv.x == mine && (j0 + 0) < lane)) ? 1 : 0;
            rk += (vv.y < mine || (vv.y == mine && (j0 + 1) < lane)) ? 1 : 0;
            rk += (vv.z < mine || (vv.z == mine && (j0 + 2) < lane)) ? 1 : 0;
            rk += (vv.w < mine || (vv.w == mine && (j0 + 3) < lane)) ? 1 : 0;
        }
        // lanes with rk<16 hold exactly the 16 smallest (lex); tau = max of their values
        float v = (rk < KNN) ? mine : -3.0e38f;
#pragma unroll
        for (int o = 32; o > 0; o >>= 1) v = fmaxf(v, __shfl_xor(v, o));
        tau[r] = v;
    }

    // ---- phase 2: filtered collection (same pipelined structure, ballot compaction) ----
    int cnt[WR];
#pragma unroll
    for (int r = 0; r < WR; ++r) cnt[r] = 0;

    {
        const float4* p = xc + lane;
        float4 a0 = p[0], a1 = p[64], a2 = p[128], a3 = p[192];
        float fl = (float)lane;
        for (int c0 = 0; c0 < NPTS; c0 += 256) {
            bool last = (c0 >= NPTS - 256);
            float4 b0, b1, b2, b3;
            if (!last) {
                const float4* pn = p + 256;
                b0 = pn[0]; b1 = pn[64]; b2 = pn[128]; b3 = pn[192];
            }
            float f0 = (float)c0 + fl;
#pragma unroll
            for (int r = 0; r < WR; ++r) {
                float v0 = vkey(xi[r], a0);
                float v1 = vkey(xi[r], a1);
                float v2 = vkey(xi[r], a2);
                float v3 = vkey(xi[r], a3);
#pragma unroll
                for (int s = 0; s < 4; ++s) {
                    float v = (s == 0) ? v0 : (s == 1) ? v1 : (s == 2) ? v2 : v3;
                    bool pp = (v <= tau[r]);
                    unsigned long long m = __ballot(pp);
                    if (m) {
                        if (pp) {
                            int ofs = __builtin_amdgcn_mbcnt_hi((unsigned)(m >> 32),
                                      __builtin_amdgcn_mbcnt_lo((unsigned)m, 0));
                            int pos = cnt[r] + ofs;
                            if (pos < CAP) buf[wave][r][pos] = make_float2(v, f0 + (float)(s * 64));
                        }
                        cnt[r] += (int)__popcll(m);
                    }
                }
            }
            if (!last) { a0 = b0; a1 = b1; a2 = b2; a3 = b3; p += 256; }
        }
    }

    __syncthreads();   // hard ordering: all buf writes visible before phase 3 reads

    // ---- phase 3: exact top-16 of buffer by rank count ----
#pragma unroll
    for (int rr = 0; rr < WR; ++rr) {
        int n = cnt[rr];
        n = (n < CAP) ? n : CAP;
        int l1 = lane + 64;
        bool v0 = (lane < n), v1 = (l1 < n);
        float2 e0 = buf[wave][rr][v0 ? lane : 0];
        float2 e1 = buf[wave][rr][v1 ? l1 : 0];
        int r0 = 0, r1 = 0;
        for (int j = 0; j < n; ++j) {
            float2 fj = buf[wave][rr][j];   // broadcast read
            r0 += (fj.x < e0.x || (fj.x == e0.x && fj.y < e0.y)) ? 1 : 0;
            r1 += (fj.x < e1.x || (fj.x == e1.x && fj.y < e1.y)) ? 1 : 0;
        }
        size_t grow = (size_t)(b * NPTS + rowbase + rr) * KNN;
        if (v0 && r0 < KNN) ibuf[grow + r0] = (unsigned short)(int)e0.y;
        if (v1 && r1 < KNN) ibuf[grow + r1] = (unsigned short)(int)e1.y;
    }
}

// moments over the 16 selected neighbors: acc[0..8]=sum f, acc[9..53]=sum f_a f_c (upper tri)
__global__ __launch_bounds__(256) void k3_moments(const float4* __restrict__ xq,
                                                  const unsigned short* __restrict__ ibuf,
                                                  double* __restrict__ stats) {
    __shared__ float red[4][54];
    int p = blockIdx.x * 256 + threadIdx.x;
    int b = p >> 13;
    const float4* xb = xq + b * NPTS;
    const unsigned short* ib = ibuf + (size_t)p * KNN;
    float4 xi = xb[p & (NPTS - 1)];

    float acc[54];
#pragma unroll
    for (int i = 0; i < 54; ++i) acc[i] = 0.0f;

#pragma unroll
    for (int k = 0; k < KNN; ++k) {
        int j = ib[k];
        float4 cj = xb[j];
        float f[9] = {xi.x, xi.y, xi.z, cj.x - xi.x, cj.y - xi.y, cj.z - xi.z, cj.x, cj.y, cj.z};
        int t = 9;
#pragma unroll
        for (int a = 0; a < 9; ++a) {
            acc[a] += f[a];
#pragma unroll
            for (int c = a; c < 9; ++c) { acc[t] += f[a] * f[c]; ++t; }
        }
    }

#pragma unroll
    for (int i = 0; i < 54; ++i) {
        float v = acc[i];
        for (int o = 32; o > 0; o >>= 1) v += __shfl_down(v, o);
        acc[i] = v;
    }
    int lane = threadIdx.x & 63;
    int wv = threadIdx.x >> 6;
    if (lane == 0) {
#pragma unroll
        for (int i = 0; i < 54; ++i) red[wv][i] = acc[i];
    }
    __syncthreads();
    if (threadIdx.x < 54) {
        float s = red[0][threadIdx.x] + red[1][threadIdx.x] + red[2][threadIdx.x] + red[3][threadIdx.x];
        atomicAdd(&stats[threadIdx.x], (double)s);
    }
}

__global__ void k4_finalize(const double* __restrict__ stats, const float* __restrict__ W,
                            const float* __restrict__ bias, const float* __restrict__ gamma,
                            const float* __restrict__ beta, float* __restrict__ ss) {
    int d = threadIdx.x;
    if (d >= DCH) return;
    const double M = (double)NB * NPTS * KNN;  // 524288
    double w[9];
    for (int c = 0; c < 9; ++c) w[c] = (double)W[c * DCH + d];
    double mf[9];
    for (int a = 0; a < 9; ++a) mf[a] = stats[a] / M;
    double q1 = 0.0;
    for (int a = 0; a < 9; ++a) q1 += mf[a] * w[a];
    double q2 = 0.0;
    int t = 0;
    for (int a = 0; a < 9; ++a) {
        for (int c = a; c < 9; ++c) {
            double pv = stats[9 + t] / M;
            double term = pv * w[a] * w[c];
            q2 += (a == c) ? term : 2.0 * term;
            ++t;
        }
    }
    double bd = (double)bias[d];
    double mean = q1 + bd;
    double ehh = q2 + 2.0 * bd * q1 + bd * bd;
    double var = ehh - mean * mean;
    double sc = (double)gamma[d] / sqrt(var + 1e-5);
    double sh = (double)beta[d] + sc * (bd - mean);
    ss[d] = (float)sc;
    ss[DCH + d] = (float)sh;
}

// 8 threads per point, 8 channels each: h = f.W (W in regs), y = max_k relu(sc*h+sh)
__global__ __launch_bounds__(256) void k5_out(const float4* __restrict__ xq,
                                              const unsigned short* __restrict__ ibuf,
                                              const float* __restrict__ W, const float* __restrict__ ss,
                                              float* __restrict__ out) {
    __shared__ float Ws[9 * DCH];
    __shared__ float scs[DCH], shs[DCH];
    for (int i = threadIdx.x; i < 9 * DCH; i += 256) Ws[i] = W[i];
    if (threadIdx.x < DCH) {
        scs[threadIdx.x] = ss[threadIdx.x];
        shs[threadIdx.x] = ss[DCH + threadIdx.x];
    }
    __syncthreads();

    int pt = blockIdx.x * 32 + (threadIdx.x >> 3);
    int oc = (threadIdx.x & 7) * 8;
    int b = pt >> 13;
    const float4* xb = xq + b * NPTS;
    float4 xi = xb[pt & (NPTS - 1)];

    float w[9][8];
#pragma unroll
    for (int c = 0; c < 9; ++c)
#pragma unroll
        for (int d = 0; d < 8; ++d) w[c][d] = Ws[c * DCH + oc + d];
    float sc[8], sh[8], y[8];
#pragma unroll
    for (int d = 0; d < 8; ++d) {
        sc[d] = scs[oc + d];
        sh[d] = shs[oc + d];
        y[d] = 0.0f;
    }

    const unsigned short* ib = ibuf + (size_t)pt * KNN;
#pragma unroll
    for (int k = 0; k < KNN; ++k) {
        int j = ib[k];
        float4 cj = xb[j];
        float f[9] = {xi.x, xi.y, xi.z, cj.x - xi.x, cj.y - xi.y, cj.z - xi.z, cj.x, cj.y, cj.z};
        float h[8];
#pragma unroll
        for (int d = 0; d < 8; ++d) h[d] = 0.0f;
#pragma unroll
        for (int c = 0; c < 9; ++c)
#pragma unroll
            for (int d = 0; d < 8; ++d) h[d] = __fmaf_rn(f[c], w[c][d], h[d]);
#pragma unroll
        for (int d = 0; d < 8; ++d) {
            float v = __fmaf_rn(sc[d], h[d], sh[d]);
            y[d] = fmaxf(y[d], fmaxf(v, 0.0f));
        }
    }
    float4* o4 = (float4*)(out + (size_t)pt * DCH + oc);
    o4[0] = make_float4(y[0], y[1], y[2], y[3]);
    o4[1] = make_float4(y[4], y[5], y[6], y[7]);
}

extern "C" void kernel_launch(void* const* d_in, const int* in_sizes, int n_in,
                              void* d_out, int out_size, void* d_ws, size_t ws_size,
                              hipStream_t stream) {
    const float* x = (const float*)d_in[0];
    const float* W = (const float*)d_in[1];
    const float* bias = (const float*)d_in[2];
    const float* gamma = (const float*)d_in[3];
    const float* beta = (const float*)d_in[4];
    float* out = (float*)d_out;
    char* ws = (char*)d_ws;

    float4* xq = (float4*)(ws + WS_XQ);
    float4* xs = (float4*)(ws + WS_XS);
    unsigned short* ibuf = (unsigned short*)(ws + WS_IB);
    double* stats = (double*)(ws + WS_ST);
    float* ss = (float*)(ws + WS_SS);

    hipMemsetAsync(stats, 0, 54 * sizeof(double), stream);
    k1_prep<<<128, 256, 0, stream>>>(x, xq, xs);
    k2_knn<<<1024, 256, 0, stream>>>(xq, xs, ibuf);
    k3_moments<<<128, 256, 0, stream>>>(xq, ibuf, stats);
    k4_finalize<<<1, 64, 0, stream>>>(stats, W, bias, gamma, beta, ss);
    k5_out<<<1024, 256, 0, stream>>>(xq, ibuf, W, ss, out);
}